// Round 1
// baseline (553.326 us; speedup 1.0000x reference)
//
#include <hip/hip_runtime.h>
#include <stdint.h>
#include <stddef.h>

// ---------------------------------------------------------------------------
// CSTreeLSTM on gfx950. Levels 1,16,256,4096,65536 (x offsets 0,1,17,273,4369).
// Round 9: software-pipelined K-loop in k_level / k_fc_combine — double-
// buffered LDS K-tiles, loads for tile t+1 issued at top of compute(t), raw
// s_barrier + explicit vmcnt(0) drain of *old* loads (one barrier per 64-K
// instead of two full __syncthreads drains), s_setprio(1) around MFMA cluster.
// Epilogue trim: tanh via 2*sig(2x)-1 (5 ops, clamp-free, inf-safe) and f2bf
// via native (__bf16) cast (v_cvt_pk_bf16_f32). XCD swizzle retained.
// ---------------------------------------------------------------------------

typedef __bf16 bf16x8 __attribute__((ext_vector_type(8)));
typedef float  f32x4  __attribute__((ext_vector_type(4)));
typedef void __attribute__((address_space(3))) lds_void_t;
typedef void __attribute__((address_space(1))) gbl_void_t;

__device__ __forceinline__ uint16_t f2bf(float f) {
  union { __bf16 b; uint16_t u; } v;
  v.b = (__bf16)f;              // RTNE, compiler emits v_cvt_pk_bf16_f32
  return v.u;
}
__device__ __forceinline__ float bf2f(uint16_t u) {
  union { uint32_t u; float f; } v; v.u = (uint32_t)u << 16;
  return v.f;
}
// native v_rcp_f32 (~1 ulp) -- error budget is huge
__device__ __forceinline__ float sig_(float x) {
  return __builtin_amdgcn_rcpf(1.0f + __expf(-x));
}
// tanh(x) = 2/(1+exp(-2x)) - 1 : mul+exp+add+rcp+fma, no clamp needed
// (x->-inf: exp=inf, rcp(inf)=0, result -1; x->+inf: exp=0, result +1)
__device__ __forceinline__ float tanh_(float x) {
  return __builtin_fmaf(2.f,
      __builtin_amdgcn_rcpf(1.f + __expf(-2.f * x)), -1.f);
}

// ---- converts --------------------------------------------------------------
__global__ void k_conv_x(const float4* __restrict__ src,
                         ushort4* __restrict__ dst, long n4) {
  long i = blockIdx.x * (long)blockDim.x + threadIdx.x;
  long stride = (long)gridDim.x * blockDim.x;
  for (; i < n4; i += stride) {
    float4 v = src[i];
    ushort4 r;
    r.x = f2bf(v.x); r.y = f2bf(v.y); r.z = f2bf(v.z); r.w = f2bf(v.w);
    dst[i] = r;
  }
}
__global__ void k_conv_w(const float4* __restrict__ w0,
                         const float4* __restrict__ w1,
                         const float4* __restrict__ w2,
                         const float4* __restrict__ w3,
                         ushort4* __restrict__ dst) {
  const long per4 = (long)512 * 1024 / 4;
  long i = blockIdx.x * (long)blockDim.x + threadIdx.x;
  long stride = (long)gridDim.x * blockDim.x;
  for (; i < 4 * per4; i += stride) {
    long seg = i / per4, off2 = i - seg * per4;
    const float4* s = (seg == 0) ? w0 : (seg == 1) ? w1 : (seg == 2) ? w2 : w3;
    float4 v = s[off2];
    ushort4 r;
    r.x = f2bf(v.x); r.y = f2bf(v.y); r.z = f2bf(v.z); r.w = f2bf(v.w);
    dst[i] = r;
  }
}

#define BM 128
#define BN 128
#define BK 32

// ---- plain bf16 GEMM (FxAll only, 140 blocks, cold path) -------------------
__global__ __launch_bounds__(256)
void k_gemm_bt(const uint16_t* __restrict__ A, int lda,
               const uint16_t* __restrict__ B, int ldb,
               float* __restrict__ C, int ldc, int K) {
  __shared__ uint16_t As[BM * BK];
  __shared__ uint16_t Bs[BN * BK];
  const int tid = threadIdx.x, lane = tid & 63, wave = tid >> 6;
  const int lrow = lane & 15, quad = lane >> 4;
  const int wm = (wave >> 1) * 64, wn = (wave & 1) * 64;
  const long tm = blockIdx.x, tn = blockIdx.y;
  f32x4 acc[4][4] = {};
  const int srow = lane >> 2, scol = (lane & 3) * 8;
  for (int k0 = 0; k0 < K; k0 += BK) {
#pragma unroll
    for (int i = 0; i < 2; ++i) {
      int row = i * 64 + wave * 16 + srow;
      const uint16_t* gp = A + (tm * BM + row) * (long)lda + k0 + scol;
      __builtin_amdgcn_global_load_lds((gbl_void_t*)(uintptr_t)gp,
          (lds_void_t*)&As[i * 2048 + wave * 512], 16, 0, 0);
    }
#pragma unroll
    for (int i = 0; i < 2; ++i) {
      int row = i * 64 + wave * 16 + srow;
      const uint16_t* gp = B + (tn * BN + row) * (long)ldb + k0 + scol;
      __builtin_amdgcn_global_load_lds((gbl_void_t*)(uintptr_t)gp,
          (lds_void_t*)&Bs[i * 2048 + wave * 512], 16, 0, 0);
    }
    __syncthreads();
    bf16x8 a[4], b[4];
#pragma unroll
    for (int f = 0; f < 4; ++f)
      a[f] = *(const bf16x8*)&As[(wm + f * 16 + lrow) * BK + quad * 8];
#pragma unroll
    for (int f = 0; f < 4; ++f)
      b[f] = *(const bf16x8*)&Bs[(wn + f * 16 + lrow) * BK + quad * 8];
#pragma unroll
    for (int fm = 0; fm < 4; ++fm)
#pragma unroll
      for (int fn = 0; fn < 4; ++fn)
        acc[fm][fn] = __builtin_amdgcn_mfma_f32_16x16x32_bf16(
            a[fm], b[fn], acc[fm][fn], 0, 0, 0);
    __syncthreads();
  }
#pragma unroll
  for (int fm = 0; fm < 4; ++fm)
#pragma unroll
    for (int fn = 0; fn < 4; ++fn) {
      long col  = tn * BN + wn + fn * 16 + lrow;
      long row0 = tm * BM + wm + fm * 16 + quad * 4;
#pragma unroll
      for (int r = 0; r < 4; ++r)
        C[(row0 + r) * (long)ldc + col] = acc[fm][fn][r];
    }
}

// ---- fused level kernel (software-pipelined) -------------------------------
// 1-D grid of nTm*8 blocks; XCD swizzle: x=b&7 (XCD), contiguous tm range per
// XCD, tn fastest. K-tile = 64 (two 32-panels), double-buffered LDS; tile t+1
// loads issued at top of compute(t); one raw barrier per tile with vmcnt(0)
// draining only tile-old loads. 80 KB LDS -> 2 blocks/CU.
template <bool HAS_F>
__global__ __launch_bounds__(256, 2)
void k_level(const uint16_t* __restrict__ A, int lda, int K,
             const uint16_t* __restrict__ Wg,
             const float* __restrict__ bi, const float* __restrict__ bo,
             const float* __restrict__ bu,
             const float* __restrict__ Fpart,
             uint16_t* __restrict__ Cbf,
             const uint16_t* __restrict__ Xnext,
             uint16_t* __restrict__ xh_next) {
  __shared__ uint16_t As[2][2][128 * 32];      // [buf][half] 32 KB
  __shared__ uint16_t Bs[2][2][3 * 64 * 32];   // [buf][half] 48 KB
  const int tid = threadIdx.x, lane = tid & 63, wave = tid >> 6;
  const int lrow = lane & 15, quad = lane >> 4;
  const int wm = (wave >> 1) * 64, wn = (wave & 1) * 32;

  long tm, tn;
  {
    const int nTm = (int)(gridDim.x >> 3);
    int b = blockIdx.x;
    if ((nTm & 7) == 0) {           // XCD swizzle (dispatch round-robin mod 8)
      int x = b & 7, j = b >> 3, per = nTm >> 3;
      tn = j & 7; tm = (long)x * per + (j >> 3);
    } else { tm = b >> 3; tn = b & 7; }
  }

  f32x4 acc[3][4][2] = {};
  const int srow = lane >> 2, scol = (lane & 3) * 8;

  auto stage = [&](int kt, int buf) {
#pragma unroll
    for (int h = 0; h < 2; ++h) {
      int kk = kt * 64 + h * 32;
#pragma unroll
      for (int i = 0; i < 2; ++i) {
        int row = i * 64 + wave * 16 + srow;
        const uint16_t* gp = A + (tm * 128 + row) * (long)lda + kk + scol;
        __builtin_amdgcn_global_load_lds((gbl_void_t*)(uintptr_t)gp,
            (lds_void_t*)&As[buf][h][i * 2048 + wave * 512], 16, 0, 0);
      }
#pragma unroll
      for (int g = 0; g < 3; ++g) {
        long grow = g * 512 + tn * 64 + wave * 16 + srow;
        const uint16_t* gp = Wg + grow * 1024 + kk + scol;
        __builtin_amdgcn_global_load_lds((gbl_void_t*)(uintptr_t)gp,
            (lds_void_t*)&Bs[buf][h][g * 2048 + wave * 512], 16, 0, 0);
      }
    }
  };

  auto compute = [&](int buf) {
#pragma unroll
    for (int h = 0; h < 2; ++h) {
      bf16x8 a[4];
#pragma unroll
      for (int f = 0; f < 4; ++f)
        a[f] = *(const bf16x8*)&As[buf][h][(wm + f * 16 + lrow) * 32 +
                                           quad * 8];
#pragma unroll
      for (int g = 0; g < 3; ++g) {
        bf16x8 b0 = *(const bf16x8*)&Bs[buf][h][g * 2048 + (wn + lrow) * 32 +
                                                quad * 8];
        bf16x8 b1 = *(const bf16x8*)&Bs[buf][h][g * 2048 +
                                                (wn + 16 + lrow) * 32 +
                                                quad * 8];
#pragma unroll
        for (int fm = 0; fm < 4; ++fm) {
          acc[g][fm][0] = __builtin_amdgcn_mfma_f32_16x16x32_bf16(
              a[fm], b0, acc[g][fm][0], 0, 0, 0);
          acc[g][fm][1] = __builtin_amdgcn_mfma_f32_16x16x32_bf16(
              a[fm], b1, acc[g][fm][1], 0, 0, 0);
        }
      }
    }
  };

  const int NT = K >> 6;            // 8 (leaf) or 16 (upper) — always even
  stage(0, 0);
  asm volatile("s_waitcnt vmcnt(0)" ::: "memory");
  __builtin_amdgcn_s_barrier();
  for (int kt = 0; kt < NT; kt += 2) {
    stage(kt + 1, 1);                       // issue-early: t+1 in flight
    __builtin_amdgcn_s_setprio(1);
    compute(0);                             // ~1.9K cyc of MFMA covers latency
    __builtin_amdgcn_s_setprio(0);
    asm volatile("s_waitcnt vmcnt(0)" ::: "memory");  // drains OLD loads only
    __builtin_amdgcn_s_barrier();
    if (kt + 2 < NT) stage(kt + 2, 0);
    __builtin_amdgcn_s_setprio(1);
    compute(1);
    __builtin_amdgcn_s_setprio(0);
    asm volatile("s_waitcnt vmcnt(0)" ::: "memory");
    __builtin_amdgcn_s_barrier();
  }

  // epilogue — C/D layout: col = lane&15, row = quad*4 + r  [HW-verified]
#pragma unroll
  for (int fn = 0; fn < 2; ++fn) {
    long col = tn * 64 + wn + fn * 16 + lrow;
    float biv = bi[col], bov = bo[col], buv = bu[col];
#pragma unroll
    for (int fm = 0; fm < 4; ++fm) {
      long row0 = tm * 128 + wm + fm * 16 + quad * 4;
      long pg   = tm * 8 + (wm >> 4) + fm;
      float hs = 0.f;
#pragma unroll
      for (int r = 0; r < 4; ++r) {
        long row = row0 + r;
        float iv = sig_(acc[0][fm][fn][r] + biv);
        float ov = sig_(acc[1][fm][fn][r] + bov);
        float uv = tanh_(acc[2][fm][fn][r] + buv);
        float c  = iv * uv;
        if (HAS_F) c += Fpart[row * 512 + col];
        Cbf[row * 512 + col] = f2bf(c);
        hs += ov * tanh_(c);
      }
      hs += __shfl_xor(hs, 16, 64);
      hs += __shfl_xor(hs, 32, 64);
      if (quad == 0) {
        xh_next[pg * 1024 + col]       = Xnext[pg * 512 + col];
        xh_next[pg * 1024 + 512 + col] = f2bf(hs);
      }
    }
  }
}

// ---- fc GEMM + fused forget-combine (software-pipelined) -------------------
__global__ __launch_bounds__(256, 2)
void k_fc_combine(const uint16_t* __restrict__ Cbf,
                  const uint16_t* __restrict__ Wfc, int ldb,
                  const float* __restrict__ Fx,
                  const float* __restrict__ bfb,
                  float* __restrict__ Fpart) {
  __shared__ uint16_t As[2][2][BM * BK];   // 32 KB
  __shared__ uint16_t Bs[2][2][BN * BK];   // 32 KB
  const int tid = threadIdx.x, lane = tid & 63, wave = tid >> 6;
  const int lrow = lane & 15, quad = lane >> 4;
  const int wm = (wave >> 1) * 64, wn = (wave & 1) * 64;
  long tm, tn;
  {
    const int nTm = (int)(gridDim.x >> 2);
    int b = blockIdx.x;
    if ((nTm & 7) == 0) {
      int x = b & 7, j = b >> 3, per = nTm >> 3;
      tn = j & 3; tm = (long)x * per + (j >> 2);
    } else { tm = b >> 2; tn = b & 3; }
  }
  const int lda = 512;
  f32x4 acc[4][4] = {};
  const int srow = lane >> 2, scol = (lane & 3) * 8;

  auto stage = [&](int kt, int buf) {
#pragma unroll
    for (int h = 0; h < 2; ++h) {
      int kk = kt * 64 + h * 32;
#pragma unroll
      for (int i = 0; i < 2; ++i) {
        int row = i * 64 + wave * 16 + srow;
        const uint16_t* gp = Cbf + (tm * BM + row) * (long)lda + kk + scol;
        __builtin_amdgcn_global_load_lds((gbl_void_t*)(uintptr_t)gp,
            (lds_void_t*)&As[buf][h][i * 2048 + wave * 512], 16, 0, 0);
      }
#pragma unroll
      for (int i = 0; i < 2; ++i) {
        int row = i * 64 + wave * 16 + srow;
        const uint16_t* gp = Wfc + (tn * BN + row) * (long)ldb + kk + scol;
        __builtin_amdgcn_global_load_lds((gbl_void_t*)(uintptr_t)gp,
            (lds_void_t*)&Bs[buf][h][i * 2048 + wave * 512], 16, 0, 0);
      }
    }
  };

  auto compute = [&](int buf) {
#pragma unroll
    for (int h = 0; h < 2; ++h) {
      bf16x8 a[4], b[4];
#pragma unroll
      for (int f = 0; f < 4; ++f)
        a[f] = *(const bf16x8*)&As[buf][h][(wm + f * 16 + lrow) * BK +
                                           quad * 8];
#pragma unroll
      for (int f = 0; f < 4; ++f)
        b[f] = *(const bf16x8*)&Bs[buf][h][(wn + f * 16 + lrow) * BK +
                                           quad * 8];
#pragma unroll
      for (int fm = 0; fm < 4; ++fm)
#pragma unroll
        for (int fn = 0; fn < 4; ++fn)
          acc[fm][fn] = __builtin_amdgcn_mfma_f32_16x16x32_bf16(
              a[fm], b[fn], acc[fm][fn], 0, 0, 0);
    }
  };

  const int NT = 8;                 // K = 512
  stage(0, 0);
  asm volatile("s_waitcnt vmcnt(0)" ::: "memory");
  __builtin_amdgcn_s_barrier();
  for (int kt = 0; kt < NT; kt += 2) {
    stage(kt + 1, 1);
    __builtin_amdgcn_s_setprio(1);
    compute(0);
    __builtin_amdgcn_s_setprio(0);
    asm volatile("s_waitcnt vmcnt(0)" ::: "memory");
    __builtin_amdgcn_s_barrier();
    if (kt + 2 < NT) stage(kt + 2, 0);
    __builtin_amdgcn_s_setprio(1);
    compute(1);
    __builtin_amdgcn_s_setprio(0);
    asm volatile("s_waitcnt vmcnt(0)" ::: "memory");
    __builtin_amdgcn_s_barrier();
  }

#pragma unroll
  for (int fm = 0; fm < 4; ++fm) {
    long pg   = tm * 8 + (wm >> 4) + fm;
    long row0 = tm * BM + wm + fm * 16 + quad * 4;
#pragma unroll
    for (int fn = 0; fn < 4; ++fn) {
      long col = tn * BN + wn + fn * 16 + lrow;
      float fx = Fx[pg * 512 + col] + bfb[col];
      float t = 0.f;
#pragma unroll
      for (int r = 0; r < 4; ++r)
        t += sig_(fx + acc[fm][fn][r]) * bf2f(Cbf[(row0 + r) * 512 + col]);
      t += __shfl_xor(t, 16, 64);
      t += __shfl_xor(t, 32, 64);
      if (quad == 0) Fpart[pg * 512 + col] = t;
    }
  }
}

// ---- wave-per-dot kernels (tiny levels) ------------------------------------
__global__ void k_dot_bb(const uint16_t* __restrict__ A, int lda,
                         const uint16_t* __restrict__ B, int ldb,
                         float* __restrict__ C, int ldc,
                         int M, int N, int K) {
  int wid  = (int)((blockIdx.x * (long)blockDim.x + threadIdx.x) >> 6);
  int lane = threadIdx.x & 63;
  if (wid >= M * N) return;
  int m = wid / N, n = wid - m * N;
  const uint16_t* a = A + (long)m * lda;
  const uint16_t* b = B + (long)n * ldb;
  int per = K >> 6, k0 = lane * per;
  float s = 0.f;
  for (int j = 0; j < per; j += 4) {
    ushort4 av = *(const ushort4*)(a + k0 + j);
    ushort4 bv = *(const ushort4*)(b + k0 + j);
    s += bf2f(av.x) * bf2f(bv.x) + bf2f(av.y) * bf2f(bv.y)
       + bf2f(av.z) * bf2f(bv.z) + bf2f(av.w) * bf2f(bv.w);
  }
#pragma unroll
  for (int off = 32; off; off >>= 1) s += __shfl_xor(s, off, 64);
  if (lane == 0) C[(long)m * ldc + n] = s;
}
__global__ void k_dot_f32(const float* __restrict__ A, int lda,
                          const float* __restrict__ B, int ldb,
                          float* __restrict__ C, int ldc,
                          int M, int N, int K) {
  int wid  = (int)((blockIdx.x * (long)blockDim.x + threadIdx.x) >> 6);
  int lane = threadIdx.x & 63;
  if (wid >= M * N) return;
  int m = wid / N, n = wid - m * N;
  const float* a = A + (long)m * lda;
  const float* b = B + (long)n * ldb;
  int per = K >> 6, k0 = lane * per;
  float s = 0.f;
  for (int j = 0; j < per; j += 4) {
    float4 av = *(const float4*)(a + k0 + j);
    float4 bv = *(const float4*)(b + k0 + j);
    s += av.x * bv.x + av.y * bv.y + av.z * bv.z + av.w * bv.w;
  }
#pragma unroll
  for (int off = 32; off; off >>= 1) s += __shfl_xor(s, off, 64);
  if (lane == 0) C[(long)m * ldc + n] = s;
}

// ---- upper-level h_sum + pack xh -------------------------------------------
__global__ void k_hsum_xh4(const float* __restrict__ Hc,
                           const uint16_t* __restrict__ xd,
                           uint16_t* __restrict__ xh, int n) {
  long idx = blockIdx.x * (long)blockDim.x + threadIdx.x;
  if (idx >= (long)n * 128) return;
  long p = idx >> 7; int hq = (int)(idx & 127) << 2;
  const float* hp = Hc + (p << 4) * 512 + hq;
  float4 s = {0.f, 0.f, 0.f, 0.f};
#pragma unroll
  for (int b = 0; b < 16; ++b) {
    float4 v = *(const float4*)(hp + b * 512);
    s.x += v.x; s.y += v.y; s.z += v.z; s.w += v.w;
  }
  *(ushort4*)(xh + p * 1024 + hq) = *(const ushort4*)(xd + p * 512 + hq);
  ushort4 hw = {f2bf(s.x), f2bf(s.y), f2bf(s.z), f2bf(s.w)};
  *(ushort4*)(xh + p * 1024 + 512 + hq) = hw;
}

// ---- separate combine (d=0 exact path) -------------------------------------
__global__ void k_combine4(const float* __restrict__ Fc,
                           const float* __restrict__ Fx,
                           const float* __restrict__ bfb,
                           const float* __restrict__ Cc,
                           float* __restrict__ Fpart, int nParents) {
  long idx = blockIdx.x * (long)blockDim.x + threadIdx.x;
  if (idx >= (long)nParents * 128) return;
  long pl = idx >> 7; int hq = (int)(idx & 127) << 2;
  float4 fxv = *(const float4*)(Fx + pl * 512 + hq);
  float4 bfv = *(const float4*)(bfb + hq);
  float fx0 = fxv.x + bfv.x, fx1 = fxv.y + bfv.y;
  float fx2 = fxv.z + bfv.z, fx3 = fxv.w + bfv.w;
  float a0 = 0.f, a1 = 0.f, a2 = 0.f, a3 = 0.f;
#pragma unroll 4
  for (int b = 0; b < 16; ++b) {
    long cl = pl * 16 + b;
    float4 f = *(const float4*)(Fc + cl * 512 + hq);
    float4 c = *(const float4*)(Cc + cl * 512 + hq);
    a0 += sig_(fx0 + f.x) * c.x;
    a1 += sig_(fx1 + f.y) * c.y;
    a2 += sig_(fx2 + f.z) * c.z;
    a3 += sig_(fx3 + f.w) * c.w;
  }
  float4 r = {a0, a1, a2, a3};
  *(float4*)(Fpart + pl * 512 + hq) = r;
}

// ---- final for tiny levels -------------------------------------------------
__global__ void k_final4(const float* __restrict__ G,
                         const float* __restrict__ Fpart,
                         const float* __restrict__ bi,
                         const float* __restrict__ bo,
                         const float* __restrict__ bu,
                         float* __restrict__ H, float* __restrict__ Cv,
                         uint16_t* __restrict__ Cbf, int n) {
  long idx = blockIdx.x * (long)blockDim.x + threadIdx.x;
  if (idx >= (long)n * 128) return;
  long p = idx >> 7; int hq = (int)(idx & 127) << 2;
  const float* g = G + p * 1536;
  float4 gi = *(const float4*)(g + hq);
  float4 go = *(const float4*)(g + 512 + hq);
  float4 gu = *(const float4*)(g + 1024 + hq);
  float4 b_i = *(const float4*)(bi + hq);
  float4 b_o = *(const float4*)(bo + hq);
  float4 b_u = *(const float4*)(bu + hq);
  float4 fp = *(const float4*)(Fpart + p * 512 + hq);
  const float* gip = &gi.x; const float* gop = &go.x; const float* gup = &gu.x;
  const float* bip = &b_i.x; const float* bop = &b_o.x; const float* bup = &b_u.x;
  const float* fpp = &fp.x;
  float4 hv, cv;
  float* hvp = &hv.x; float* cvp = &cv.x;
  ushort4 cw; unsigned short* cwp = &cw.x;
#pragma unroll
  for (int j = 0; j < 4; ++j) {
    float iv = sig_(gip[j] + bip[j]);
    float ov = sig_(gop[j] + bop[j]);
    float uv = tanh_(gup[j] + bup[j]);
    float c  = iv * uv + fpp[j];
    cvp[j] = c;
    cwp[j] = f2bf(c);
    hvp[j] = ov * tanh_(c);
  }
  *(float4*)(H  + p * 512 + hq) = hv;
  *(float4*)(Cv + p * 512 + hq) = cv;
  *(ushort4*)(Cbf + p * 512 + hq) = cw;
}

// ---------------------------------------------------------------------------
extern "C" void kernel_launch(void* const* d_in, const int* in_sizes, int n_in,
                              void* d_out, int out_size, void* d_ws, size_t ws_size,
                              hipStream_t stream) {
  const float* x    = (const float*)d_in[0];
  const float* wi_w = (const float*)d_in[1];
  const float* wi_b = (const float*)d_in[2];
  const float* wf_w = (const float*)d_in[3];
  const float* wf_b = (const float*)d_in[4];
  const float* wo_w = (const float*)d_in[5];
  const float* wo_b = (const float*)d_in[6];
  const float* wu_w = (const float*)d_in[7];
  const float* wu_b = (const float*)d_in[8];
  (void)in_sizes; (void)n_in; (void)out_size; (void)ws_size;

  static const long offs[5] = {0, 1, 17, 273, 4369};
  const long NTOT = 69905;

  // ---- workspace (~175 MB of ~573 MB) ----
  char* ws = (char*)d_ws;
  size_t off = 0;
  auto alloc = [&](size_t bytes) -> void* {
    void* p = ws + off;
    off += (bytes + 255) & ~(size_t)255;
    return p;
  };
  uint16_t* Xbf   = (uint16_t*)alloc(NTOT * 512 * 2);
  uint16_t* Wgw   = (uint16_t*)alloc((size_t)2048 * 1024 * 2);
  uint16_t* Wg    = Wgw;
  uint16_t* Wf    = Wgw + (size_t)1536 * 1024;
  float*    FxAll = (float*)alloc((size_t)4480 * 512 * 4);
  uint16_t* Cbf   = (uint16_t*)alloc((size_t)65536 * 512 * 2);
  uint16_t* CbfU  = (uint16_t*)alloc((size_t)4096 * 512 * 2);
  uint16_t* CbfU2 = (uint16_t*)alloc((size_t)256 * 512 * 2);
  uint16_t* xhA   = (uint16_t*)alloc((size_t)4096 * 1024 * 2);
  uint16_t* xhB   = (uint16_t*)alloc((size_t)256 * 1024 * 2);
  uint16_t* xhC   = (uint16_t*)alloc((size_t)16 * 1024 * 2);
  float*    Fpart = (float*)alloc((size_t)4096 * 512 * 4);
  float*    Gf    = (float*)alloc((size_t)16 * 1536 * 4);
  float*    Fc    = (float*)alloc((size_t)16 * 512 * 4);
  float*    HupA  = (float*)alloc((size_t)16 * 512 * 4);
  float*    CupA  = (float*)alloc((size_t)16 * 512 * 4);

  auto blks = [](long n) { return (int)((n + 255) / 256); };

  // ---- converts ----
  {
    long n4 = NTOT * 512 / 4;
    k_conv_x<<<8192, 256, 0, stream>>>((const float4*)x, (ushort4*)Xbf, n4);
    k_conv_w<<<2048, 256, 0, stream>>>((const float4*)wi_w, (const float4*)wo_w,
                                       (const float4*)wu_w, (const float4*)wf_w,
                                       (ushort4*)Wgw);
  }

  // ---- Fx for all upper levels (node ids 0..4368, pad to 4480) ----
  {
    dim3 grid(35, 4);
    k_gemm_bt<<<grid, 256, 0, stream>>>(Xbf, 512, Wf, 1024, FxAll, 512, 512);
  }

  // ---- leaf level (M=65536, K=512): nTm=512, 1-D swizzled grid ----
  k_level<false><<<4096, 256, 0, stream>>>(
      Xbf + offs[4] * 512, 512, 512, Wg, wi_b, wo_b, wu_b, nullptr,
      Cbf, Xbf + offs[3] * 512, xhA);
  k_fc_combine<<<2048, 256, 0, stream>>>(Cbf, Wf + 512, 1024,
                                         FxAll + offs[3] * 512, wf_b, Fpart);

  // ---- level 3 (M=4096, K=1024): nTm=32 ----
  k_level<true><<<256, 256, 0, stream>>>(
      xhA, 1024, 1024, Wg, wi_b, wo_b, wu_b, Fpart,
      CbfU, Xbf + offs[2] * 512, xhB);
  k_fc_combine<<<128, 256, 0, stream>>>(CbfU, Wf + 512, 1024,
                                        FxAll + offs[2] * 512, wf_b, Fpart);

  // ---- level 2 (M=256, K=1024): nTm=2 (plain mapping) ----
  k_level<true><<<16, 256, 0, stream>>>(
      xhB, 1024, 1024, Wg, wi_b, wo_b, wu_b, Fpart,
      CbfU2, Xbf + offs[1] * 512, xhC);
  k_fc_combine<<<8, 256, 0, stream>>>(CbfU2, Wf + 512, 1024,
                                      FxAll + offs[1] * 512, wf_b, Fpart);

  // ---- level 1 (n=16) ----
  {
    long waves = 16L * 1536;
    k_dot_bb<<<(int)((waves * 64 + 255) / 256), 256, 0, stream>>>(
        xhC, 1024, Wg, 1024, Gf, 1536, 16, 1536, 1024);
    k_final4<<<blks(16L * 128), 256, 0, stream>>>(
        Gf, Fpart, wi_b, wo_b, wu_b, HupA, CupA, CbfU2, 16);
  }

  // ---- level 0 (root, exact fp32 fc path) ----
  k_hsum_xh4<<<1, 256, 0, stream>>>(HupA, Xbf + offs[0] * 512, xhC, 1);
  {
    long waves = 1536;
    k_dot_bb<<<(int)((waves * 64 + 255) / 256), 256, 0, stream>>>(
        xhC, 1024, Wg, 1024, Gf, 1536, 1, 1536, 1024);
  }
  {
    long waves = 16L * 512;
    k_dot_f32<<<(int)((waves * 64 + 255) / 256), 256, 0, stream>>>(
        CupA, 512, wf_w + 512, 1024, Fc, 512, 16, 512, 512);
  }
  k_combine4<<<1, 256, 0, stream>>>(Fc, FxAll, wf_b, CupA, Fpart, 1);
  k_final4<<<1, 256, 0, stream>>>(
      Gf, Fpart, wi_b, wo_b, wu_b,
      (float*)d_out, (float*)d_out + 512, CbfU2, 1);
}

// Round 2
// 523.768 us; speedup vs baseline: 1.0564x; 1.0564x over previous
//
#include <hip/hip_runtime.h>
#include <stdint.h>
#include <stddef.h>

// ---------------------------------------------------------------------------
// CSTreeLSTM on gfx950. Levels 1,16,256,4096,65536 (x offsets 0,1,17,273,4369).
// Round 10: revert round-9 pipelining (occupancy regression). Back to the
// 2-phase round-8 loop, but with T2 bank-conflict fix: LDS K-tiles are
// [row][64] bf16 (128B rows) with XOR chunk swizzle (phys16B = logical ^
// (row&7)); stage pre-swizzles the per-lane GLOBAL source column so the
// linear global_load_lds write lands swizzled (rule 21: both sides).
// Fragment ds_read_b128 goes 8-way-conflicted -> 2-way (free).
// Epilogue trims retained: 5-op tanh (2*sig(2x)-1, clamp-free) and native
// (__bf16) cast for f2bf. XCD swizzle retained.
// ---------------------------------------------------------------------------

typedef __bf16 bf16x8 __attribute__((ext_vector_type(8)));
typedef float  f32x4  __attribute__((ext_vector_type(4)));
typedef void __attribute__((address_space(3))) lds_void_t;
typedef void __attribute__((address_space(1))) gbl_void_t;

__device__ __forceinline__ uint16_t f2bf(float f) {
  union { __bf16 b; uint16_t u; } v;
  v.b = (__bf16)f;              // RTNE, compiler emits v_cvt_pk_bf16_f32
  return v.u;
}
__device__ __forceinline__ float bf2f(uint16_t u) {
  union { uint32_t u; float f; } v; v.u = (uint32_t)u << 16;
  return v.f;
}
// native v_rcp_f32 (~1 ulp) -- error budget is huge
__device__ __forceinline__ float sig_(float x) {
  return __builtin_amdgcn_rcpf(1.0f + __expf(-x));
}
// tanh(x) = 2/(1+exp(-2x)) - 1 : mul+exp+add+rcp+fma, no clamp needed
// (x->-inf: exp=inf, rcp(inf)=0, result -1; x->+inf: exp=0, result +1)
__device__ __forceinline__ float tanh_(float x) {
  return __builtin_fmaf(2.f,
      __builtin_amdgcn_rcpf(1.f + __expf(-2.f * x)), -1.f);
}

// ---- converts --------------------------------------------------------------
__global__ void k_conv_x(const float4* __restrict__ src,
                         ushort4* __restrict__ dst, long n4) {
  long i = blockIdx.x * (long)blockDim.x + threadIdx.x;
  long stride = (long)gridDim.x * blockDim.x;
  for (; i < n4; i += stride) {
    float4 v = src[i];
    ushort4 r;
    r.x = f2bf(v.x); r.y = f2bf(v.y); r.z = f2bf(v.z); r.w = f2bf(v.w);
    dst[i] = r;
  }
}
__global__ void k_conv_w(const float4* __restrict__ w0,
                         const float4* __restrict__ w1,
                         const float4* __restrict__ w2,
                         const float4* __restrict__ w3,
                         ushort4* __restrict__ dst) {
  const long per4 = (long)512 * 1024 / 4;
  long i = blockIdx.x * (long)blockDim.x + threadIdx.x;
  long stride = (long)gridDim.x * blockDim.x;
  for (; i < 4 * per4; i += stride) {
    long seg = i / per4, off2 = i - seg * per4;
    const float4* s = (seg == 0) ? w0 : (seg == 1) ? w1 : (seg == 2) ? w2 : w3;
    float4 v = s[off2];
    ushort4 r;
    r.x = f2bf(v.x); r.y = f2bf(v.y); r.z = f2bf(v.z); r.w = f2bf(v.w);
    dst[i] = r;
  }
}

#define BM 128
#define BN 128
#define BK 32

// ---- plain bf16 GEMM (FxAll only, cold path, 140 blocks) -------------------
__global__ __launch_bounds__(256)
void k_gemm_bt(const uint16_t* __restrict__ A, int lda,
               const uint16_t* __restrict__ B, int ldb,
               float* __restrict__ C, int ldc, int K) {
  __shared__ uint16_t As[BM * BK];
  __shared__ uint16_t Bs[BN * BK];
  const int tid = threadIdx.x, lane = tid & 63, wave = tid >> 6;
  const int lrow = lane & 15, quad = lane >> 4;
  const int wm = (wave >> 1) * 64, wn = (wave & 1) * 64;
  const long tm = blockIdx.x, tn = blockIdx.y;
  f32x4 acc[4][4] = {};
  const int srow = lane >> 2, scol = (lane & 3) * 8;
  for (int k0 = 0; k0 < K; k0 += BK) {
#pragma unroll
    for (int i = 0; i < 2; ++i) {
      int row = i * 64 + wave * 16 + srow;
      const uint16_t* gp = A + (tm * BM + row) * (long)lda + k0 + scol;
      __builtin_amdgcn_global_load_lds((gbl_void_t*)(uintptr_t)gp,
          (lds_void_t*)&As[i * 2048 + wave * 512], 16, 0, 0);
    }
#pragma unroll
    for (int i = 0; i < 2; ++i) {
      int row = i * 64 + wave * 16 + srow;
      const uint16_t* gp = B + (tn * BN + row) * (long)ldb + k0 + scol;
      __builtin_amdgcn_global_load_lds((gbl_void_t*)(uintptr_t)gp,
          (lds_void_t*)&Bs[i * 2048 + wave * 512], 16, 0, 0);
    }
    __syncthreads();
    bf16x8 a[4], b[4];
#pragma unroll
    for (int f = 0; f < 4; ++f)
      a[f] = *(const bf16x8*)&As[(wm + f * 16 + lrow) * BK + quad * 8];
#pragma unroll
    for (int f = 0; f < 4; ++f)
      b[f] = *(const bf16x8*)&Bs[(wn + f * 16 + lrow) * BK + quad * 8];
#pragma unroll
    for (int fm = 0; fm < 4; ++fm)
#pragma unroll
      for (int fn = 0; fn < 4; ++fn)
        acc[fm][fn] = __builtin_amdgcn_mfma_f32_16x16x32_bf16(
            a[fm], b[fn], acc[fm][fn], 0, 0, 0);
    __syncthreads();
  }
#pragma unroll
  for (int fm = 0; fm < 4; ++fm)
#pragma unroll
    for (int fn = 0; fn < 4; ++fn) {
      long col  = tn * BN + wn + fn * 16 + lrow;
      long row0 = tm * BM + wm + fm * 16 + quad * 4;
#pragma unroll
      for (int r = 0; r < 4; ++r)
        C[(row0 + r) * (long)ldc + col] = acc[fm][fn][r];
    }
}

// ---- fused level kernel ----------------------------------------------------
// 1-D grid of nTm*8 blocks; XCD swizzle: x=b&7 (XCD), contiguous tm range per
// XCD, tn fastest. 2-phase loop (stage 64-K tile, sync, compute, sync).
// LDS layout: As[row][64], Bs[g*64+row][64] bf16; 16B chunks XOR-swizzled by
// (row&7). Stage pre-swizzles global src col; reads XOR the chunk index.
template <bool HAS_F>
__global__ __launch_bounds__(256, 3)
void k_level(const uint16_t* __restrict__ A, int lda, int K,
             const uint16_t* __restrict__ Wg,
             const float* __restrict__ bi, const float* __restrict__ bo,
             const float* __restrict__ bu,
             const float* __restrict__ Fpart,
             uint16_t* __restrict__ Cbf,
             const uint16_t* __restrict__ Xnext,
             uint16_t* __restrict__ xh_next) {
  __shared__ uint16_t As[128 * 64];      // 16 KB
  __shared__ uint16_t Bs[192 * 64];      // 24 KB
  const int tid = threadIdx.x, lane = tid & 63, wave = tid >> 6;
  const int lrow = lane & 15, quad = lane >> 4;
  const int wm = (wave >> 1) * 64, wn = (wave & 1) * 32;

  long tm, tn;
  {
    const int nTm = (int)(gridDim.x >> 3);
    int b = blockIdx.x;
    if ((nTm & 7) == 0) {           // XCD swizzle (dispatch round-robin mod 8)
      int x = b & 7, j = b >> 3, per = nTm >> 3;
      tn = j & 7; tm = (long)x * per + (j >> 3);
    } else { tm = b >> 3; tn = b & 7; }
  }

  f32x4 acc[3][4][2] = {};

  // stage mapping: each 1KB wave-store = 8 rows x 8 chunks of 16B.
  // lane -> (row srow, physical chunk lane&7); fetch logical chunk
  // (lane&7)^srow so phys = logical ^ (row&7).
  const int srow = lane >> 3;
  const int scol = (((lane & 7) ^ srow) << 3);     // elements
  // read chunk byte offsets (elements): logical chunk h*4+quad, phys ^ (row&7)
  const int rsw = lrow & 7;
  const int pc[2] = { ((0 + quad) ^ rsw) << 3, ((4 + quad) ^ rsw) << 3 };

  for (int k0 = 0; k0 < K; k0 += 64) {
#pragma unroll
    for (int j = 0; j < 4; ++j) {            // A: rows wave*32 .. +31
      int row = wave * 32 + j * 8 + srow;
      const uint16_t* gp = A + (tm * 128 + row) * (long)lda + k0 + scol;
      __builtin_amdgcn_global_load_lds((gbl_void_t*)(uintptr_t)gp,
          (lds_void_t*)&As[(wave * 32 + j * 8) * 64], 16, 0, 0);
    }
#pragma unroll
    for (int j = 0; j < 6; ++j) {            // B: 24 chunks of 8 rows
      int cc = wave * 6 + j;
      int g  = cc >> 3;
      long grow = (long)g * 512 + tn * 64 + (cc & 7) * 8 + srow;
      const uint16_t* gp = Wg + grow * 1024 + k0 + scol;
      __builtin_amdgcn_global_load_lds((gbl_void_t*)(uintptr_t)gp,
          (lds_void_t*)&Bs[cc * 512], 16, 0, 0);
    }
    __syncthreads();

#pragma unroll
    for (int h = 0; h < 2; ++h) {
      bf16x8 a[4];
#pragma unroll
      for (int f = 0; f < 4; ++f)
        a[f] = *(const bf16x8*)&As[(wm + f * 16 + lrow) * 64 + pc[h]];
#pragma unroll
      for (int g = 0; g < 3; ++g) {
        bf16x8 b0 = *(const bf16x8*)&Bs[(g * 64 + wn + lrow) * 64 + pc[h]];
        bf16x8 b1 = *(const bf16x8*)&Bs[(g * 64 + wn + 16 + lrow) * 64 +
                                        pc[h]];
#pragma unroll
        for (int fm = 0; fm < 4; ++fm) {
          acc[g][fm][0] = __builtin_amdgcn_mfma_f32_16x16x32_bf16(
              a[fm], b0, acc[g][fm][0], 0, 0, 0);
          acc[g][fm][1] = __builtin_amdgcn_mfma_f32_16x16x32_bf16(
              a[fm], b1, acc[g][fm][1], 0, 0, 0);
        }
      }
    }
    __syncthreads();
  }

  // epilogue — C/D layout: col = lane&15, row = quad*4 + r  [HW-verified]
#pragma unroll
  for (int fn = 0; fn < 2; ++fn) {
    long col = tn * 64 + wn + fn * 16 + lrow;
    float biv = bi[col], bov = bo[col], buv = bu[col];
#pragma unroll
    for (int fm = 0; fm < 4; ++fm) {
      long row0 = tm * 128 + wm + fm * 16 + quad * 4;
      long pg   = tm * 8 + (wm >> 4) + fm;
      float hs = 0.f;
#pragma unroll
      for (int r = 0; r < 4; ++r) {
        long row = row0 + r;
        float iv = sig_(acc[0][fm][fn][r] + biv);
        float ov = sig_(acc[1][fm][fn][r] + bov);
        float uv = tanh_(acc[2][fm][fn][r] + buv);
        float c  = iv * uv;
        if (HAS_F) c += Fpart[row * 512 + col];
        Cbf[row * 512 + col] = f2bf(c);
        hs += ov * tanh_(c);
      }
      hs += __shfl_xor(hs, 16, 64);
      hs += __shfl_xor(hs, 32, 64);
      if (quad == 0) {
        xh_next[pg * 1024 + col]       = Xnext[pg * 512 + col];
        xh_next[pg * 1024 + 512 + col] = f2bf(hs);
      }
    }
  }
}

// ---- fc GEMM + fused forget-combine (XCD-swizzled, swizzled LDS) -----------
__global__ __launch_bounds__(256, 3)
void k_fc_combine(const uint16_t* __restrict__ Cbf,
                  const uint16_t* __restrict__ Wfc, int ldb,
                  const float* __restrict__ Fx,
                  const float* __restrict__ bfb,
                  float* __restrict__ Fpart) {
  __shared__ uint16_t As[128 * 64];   // 16 KB
  __shared__ uint16_t Bs[128 * 64];   // 16 KB
  const int tid = threadIdx.x, lane = tid & 63, wave = tid >> 6;
  const int lrow = lane & 15, quad = lane >> 4;
  const int wm = (wave >> 1) * 64, wn = (wave & 1) * 64;
  long tm, tn;
  {
    const int nTm = (int)(gridDim.x >> 2);
    int b = blockIdx.x;
    if ((nTm & 7) == 0) {
      int x = b & 7, j = b >> 3, per = nTm >> 3;
      tn = j & 3; tm = (long)x * per + (j >> 2);
    } else { tm = b >> 2; tn = b & 3; }
  }
  const int lda = 512;
  f32x4 acc[4][4] = {};

  const int srow = lane >> 3;
  const int scol = (((lane & 7) ^ srow) << 3);
  const int rsw = lrow & 7;
  const int pc[2] = { ((0 + quad) ^ rsw) << 3, ((4 + quad) ^ rsw) << 3 };

  for (int k0 = 0; k0 < 512; k0 += 64) {
#pragma unroll
    for (int j = 0; j < 4; ++j) {
      int row = wave * 32 + j * 8 + srow;
      const uint16_t* gp = Cbf + (tm * BM + row) * (long)lda + k0 + scol;
      __builtin_amdgcn_global_load_lds((gbl_void_t*)(uintptr_t)gp,
          (lds_void_t*)&As[(wave * 32 + j * 8) * 64], 16, 0, 0);
    }
#pragma unroll
    for (int j = 0; j < 4; ++j) {
      int row = wave * 32 + j * 8 + srow;
      const uint16_t* gp = Wfc + (tn * BN + row) * (long)ldb + k0 + scol;
      __builtin_amdgcn_global_load_lds((gbl_void_t*)(uintptr_t)gp,
          (lds_void_t*)&Bs[(wave * 32 + j * 8) * 64], 16, 0, 0);
    }
    __syncthreads();
#pragma unroll
    for (int h = 0; h < 2; ++h) {
      bf16x8 a[4], b[4];
#pragma unroll
      for (int f = 0; f < 4; ++f)
        a[f] = *(const bf16x8*)&As[(wm + f * 16 + lrow) * 64 + pc[h]];
#pragma unroll
      for (int f = 0; f < 4; ++f)
        b[f] = *(const bf16x8*)&Bs[(wn + f * 16 + lrow) * 64 + pc[h]];
#pragma unroll
      for (int fm = 0; fm < 4; ++fm)
#pragma unroll
        for (int fn = 0; fn < 4; ++fn)
          acc[fm][fn] = __builtin_amdgcn_mfma_f32_16x16x32_bf16(
              a[fm], b[fn], acc[fm][fn], 0, 0, 0);
    }
    __syncthreads();
  }
#pragma unroll
  for (int fm = 0; fm < 4; ++fm) {
    long pg   = tm * 8 + (wm >> 4) + fm;
    long row0 = tm * BM + wm + fm * 16 + quad * 4;
#pragma unroll
    for (int fn = 0; fn < 4; ++fn) {
      long col = tn * BN + wn + fn * 16 + lrow;
      float fx = Fx[pg * 512 + col] + bfb[col];
      float t = 0.f;
#pragma unroll
      for (int r = 0; r < 4; ++r)
        t += sig_(fx + acc[fm][fn][r]) * bf2f(Cbf[(row0 + r) * 512 + col]);
      t += __shfl_xor(t, 16, 64);
      t += __shfl_xor(t, 32, 64);
      if (quad == 0) Fpart[pg * 512 + col] = t;
    }
  }
}

// ---- wave-per-dot kernels (tiny levels) ------------------------------------
__global__ void k_dot_bb(const uint16_t* __restrict__ A, int lda,
                         const uint16_t* __restrict__ B, int ldb,
                         float* __restrict__ C, int ldc,
                         int M, int N, int K) {
  int wid  = (int)((blockIdx.x * (long)blockDim.x + threadIdx.x) >> 6);
  int lane = threadIdx.x & 63;
  if (wid >= M * N) return;
  int m = wid / N, n = wid - m * N;
  const uint16_t* a = A + (long)m * lda;
  const uint16_t* b = B + (long)n * ldb;
  int per = K >> 6, k0 = lane * per;
  float s = 0.f;
  for (int j = 0; j < per; j += 4) {
    ushort4 av = *(const ushort4*)(a + k0 + j);
    ushort4 bv = *(const ushort4*)(b + k0 + j);
    s += bf2f(av.x) * bf2f(bv.x) + bf2f(av.y) * bf2f(bv.y)
       + bf2f(av.z) * bf2f(bv.z) + bf2f(av.w) * bf2f(bv.w);
  }
#pragma unroll
  for (int off = 32; off; off >>= 1) s += __shfl_xor(s, off, 64);
  if (lane == 0) C[(long)m * ldc + n] = s;
}
__global__ void k_dot_f32(const float* __restrict__ A, int lda,
                          const float* __restrict__ B, int ldb,
                          float* __restrict__ C, int ldc,
                          int M, int N, int K) {
  int wid  = (int)((blockIdx.x * (long)blockDim.x + threadIdx.x) >> 6);
  int lane = threadIdx.x & 63;
  if (wid >= M * N) return;
  int m = wid / N, n = wid - m * N;
  const float* a = A + (long)m * lda;
  const float* b = B + (long)n * ldb;
  int per = K >> 6, k0 = lane * per;
  float s = 0.f;
  for (int j = 0; j < per; j += 4) {
    float4 av = *(const float4*)(a + k0 + j);
    float4 bv = *(const float4*)(b + k0 + j);
    s += av.x * bv.x + av.y * bv.y + av.z * bv.z + av.w * bv.w;
  }
#pragma unroll
  for (int off = 32; off; off >>= 1) s += __shfl_xor(s, off, 64);
  if (lane == 0) C[(long)m * ldc + n] = s;
}

// ---- upper-level h_sum + pack xh -------------------------------------------
__global__ void k_hsum_xh4(const float* __restrict__ Hc,
                           const uint16_t* __restrict__ xd,
                           uint16_t* __restrict__ xh, int n) {
  long idx = blockIdx.x * (long)blockDim.x + threadIdx.x;
  if (idx >= (long)n * 128) return;
  long p = idx >> 7; int hq = (int)(idx & 127) << 2;
  const float* hp = Hc + (p << 4) * 512 + hq;
  float4 s = {0.f, 0.f, 0.f, 0.f};
#pragma unroll
  for (int b = 0; b < 16; ++b) {
    float4 v = *(const float4*)(hp + b * 512);
    s.x += v.x; s.y += v.y; s.z += v.z; s.w += v.w;
  }
  *(ushort4*)(xh + p * 1024 + hq) = *(const ushort4*)(xd + p * 512 + hq);
  ushort4 hw = {f2bf(s.x), f2bf(s.y), f2bf(s.z), f2bf(s.w)};
  *(ushort4*)(xh + p * 1024 + 512 + hq) = hw;
}

// ---- separate combine (d=0 exact path) -------------------------------------
__global__ void k_combine4(const float* __restrict__ Fc,
                           const float* __restrict__ Fx,
                           const float* __restrict__ bfb,
                           const float* __restrict__ Cc,
                           float* __restrict__ Fpart, int nParents) {
  long idx = blockIdx.x * (long)blockDim.x + threadIdx.x;
  if (idx >= (long)nParents * 128) return;
  long pl = idx >> 7; int hq = (int)(idx & 127) << 2;
  float4 fxv = *(const float4*)(Fx + pl * 512 + hq);
  float4 bfv = *(const float4*)(bfb + hq);
  float fx0 = fxv.x + bfv.x, fx1 = fxv.y + bfv.y;
  float fx2 = fxv.z + bfv.z, fx3 = fxv.w + bfv.w;
  float a0 = 0.f, a1 = 0.f, a2 = 0.f, a3 = 0.f;
#pragma unroll 4
  for (int b = 0; b < 16; ++b) {
    long cl = pl * 16 + b;
    float4 f = *(const float4*)(Fc + cl * 512 + hq);
    float4 c = *(const float4*)(Cc + cl * 512 + hq);
    a0 += sig_(fx0 + f.x) * c.x;
    a1 += sig_(fx1 + f.y) * c.y;
    a2 += sig_(fx2 + f.z) * c.z;
    a3 += sig_(fx3 + f.w) * c.w;
  }
  float4 r = {a0, a1, a2, a3};
  *(float4*)(Fpart + pl * 512 + hq) = r;
}

// ---- final for tiny levels -------------------------------------------------
__global__ void k_final4(const float* __restrict__ G,
                         const float* __restrict__ Fpart,
                         const float* __restrict__ bi,
                         const float* __restrict__ bo,
                         const float* __restrict__ bu,
                         float* __restrict__ H, float* __restrict__ Cv,
                         uint16_t* __restrict__ Cbf, int n) {
  long idx = blockIdx.x * (long)blockDim.x + threadIdx.x;
  if (idx >= (long)n * 128) return;
  long p = idx >> 7; int hq = (int)(idx & 127) << 2;
  const float* g = G + p * 1536;
  float4 gi = *(const float4*)(g + hq);
  float4 go = *(const float4*)(g + 512 + hq);
  float4 gu = *(const float4*)(g + 1024 + hq);
  float4 b_i = *(const float4*)(bi + hq);
  float4 b_o = *(const float4*)(bo + hq);
  float4 b_u = *(const float4*)(bu + hq);
  float4 fp = *(const float4*)(Fpart + p * 512 + hq);
  const float* gip = &gi.x; const float* gop = &go.x; const float* gup = &gu.x;
  const float* bip = &b_i.x; const float* bop = &b_o.x; const float* bup = &b_u.x;
  const float* fpp = &fp.x;
  float4 hv, cv;
  float* hvp = &hv.x; float* cvp = &cv.x;
  ushort4 cw; unsigned short* cwp = &cw.x;
#pragma unroll
  for (int j = 0; j < 4; ++j) {
    float iv = sig_(gip[j] + bip[j]);
    float ov = sig_(gop[j] + bop[j]);
    float uv = tanh_(gup[j] + bup[j]);
    float c  = iv * uv + fpp[j];
    cvp[j] = c;
    cwp[j] = f2bf(c);
    hvp[j] = ov * tanh_(c);
  }
  *(float4*)(H  + p * 512 + hq) = hv;
  *(float4*)(Cv + p * 512 + hq) = cv;
  *(ushort4*)(Cbf + p * 512 + hq) = cw;
}

// ---------------------------------------------------------------------------
extern "C" void kernel_launch(void* const* d_in, const int* in_sizes, int n_in,
                              void* d_out, int out_size, void* d_ws, size_t ws_size,
                              hipStream_t stream) {
  const float* x    = (const float*)d_in[0];
  const float* wi_w = (const float*)d_in[1];
  const float* wi_b = (const float*)d_in[2];
  const float* wf_w = (const float*)d_in[3];
  const float* wf_b = (const float*)d_in[4];
  const float* wo_w = (const float*)d_in[5];
  const float* wo_b = (const float*)d_in[6];
  const float* wu_w = (const float*)d_in[7];
  const float* wu_b = (const float*)d_in[8];
  (void)in_sizes; (void)n_in; (void)out_size; (void)ws_size;

  static const long offs[5] = {0, 1, 17, 273, 4369};
  const long NTOT = 69905;

  // ---- workspace (~175 MB of ~573 MB) ----
  char* ws = (char*)d_ws;
  size_t off = 0;
  auto alloc = [&](size_t bytes) -> void* {
    void* p = ws + off;
    off += (bytes + 255) & ~(size_t)255;
    return p;
  };
  uint16_t* Xbf   = (uint16_t*)alloc(NTOT * 512 * 2);
  uint16_t* Wgw   = (uint16_t*)alloc((size_t)2048 * 1024 * 2);
  uint16_t* Wg    = Wgw;
  uint16_t* Wf    = Wgw + (size_t)1536 * 1024;
  float*    FxAll = (float*)alloc((size_t)4480 * 512 * 4);
  uint16_t* Cbf   = (uint16_t*)alloc((size_t)65536 * 512 * 2);
  uint16_t* CbfU  = (uint16_t*)alloc((size_t)4096 * 512 * 2);
  uint16_t* CbfU2 = (uint16_t*)alloc((size_t)256 * 512 * 2);
  uint16_t* xhA   = (uint16_t*)alloc((size_t)4096 * 1024 * 2);
  uint16_t* xhB   = (uint16_t*)alloc((size_t)256 * 1024 * 2);
  uint16_t* xhC   = (uint16_t*)alloc((size_t)16 * 1024 * 2);
  float*    Fpart = (float*)alloc((size_t)4096 * 512 * 4);
  float*    Gf    = (float*)alloc((size_t)16 * 1536 * 4);
  float*    Fc    = (float*)alloc((size_t)16 * 512 * 4);
  float*    HupA  = (float*)alloc((size_t)16 * 512 * 4);
  float*    CupA  = (float*)alloc((size_t)16 * 512 * 4);

  auto blks = [](long n) { return (int)((n + 255) / 256); };

  // ---- converts ----
  {
    long n4 = NTOT * 512 / 4;
    k_conv_x<<<8192, 256, 0, stream>>>((const float4*)x, (ushort4*)Xbf, n4);
    k_conv_w<<<2048, 256, 0, stream>>>((const float4*)wi_w, (const float4*)wo_w,
                                       (const float4*)wu_w, (const float4*)wf_w,
                                       (ushort4*)Wgw);
  }

  // ---- Fx for all upper levels (node ids 0..4368, pad to 4480) ----
  {
    dim3 grid(35, 4);
    k_gemm_bt<<<grid, 256, 0, stream>>>(Xbf, 512, Wf, 1024, FxAll, 512, 512);
  }

  // ---- leaf level (M=65536, K=512): nTm=512, 1-D swizzled grid ----
  k_level<false><<<4096, 256, 0, stream>>>(
      Xbf + offs[4] * 512, 512, 512, Wg, wi_b, wo_b, wu_b, nullptr,
      Cbf, Xbf + offs[3] * 512, xhA);
  k_fc_combine<<<2048, 256, 0, stream>>>(Cbf, Wf + 512, 1024,
                                         FxAll + offs[3] * 512, wf_b, Fpart);

  // ---- level 3 (M=4096, K=1024): nTm=32 ----
  k_level<true><<<256, 256, 0, stream>>>(
      xhA, 1024, 1024, Wg, wi_b, wo_b, wu_b, Fpart,
      CbfU, Xbf + offs[2] * 512, xhB);
  k_fc_combine<<<128, 256, 0, stream>>>(CbfU, Wf + 512, 1024,
                                        FxAll + offs[2] * 512, wf_b, Fpart);

  // ---- level 2 (M=256, K=1024): nTm=2 (plain mapping) ----
  k_level<true><<<16, 256, 0, stream>>>(
      xhB, 1024, 1024, Wg, wi_b, wo_b, wu_b, Fpart,
      CbfU2, Xbf + offs[1] * 512, xhC);
  k_fc_combine<<<8, 256, 0, stream>>>(CbfU2, Wf + 512, 1024,
                                      FxAll + offs[1] * 512, wf_b, Fpart);

  // ---- level 1 (n=16) ----
  {
    long waves = 16L * 1536;
    k_dot_bb<<<(int)((waves * 64 + 255) / 256), 256, 0, stream>>>(
        xhC, 1024, Wg, 1024, Gf, 1536, 16, 1536, 1024);
    k_final4<<<blks(16L * 128), 256, 0, stream>>>(
        Gf, Fpart, wi_b, wo_b, wu_b, HupA, CupA, CbfU2, 16);
  }

  // ---- level 0 (root, exact fp32 fc path) ----
  k_hsum_xh4<<<1, 256, 0, stream>>>(HupA, Xbf + offs[0] * 512, xhC, 1);
  {
    long waves = 1536;
    k_dot_bb<<<(int)((waves * 64 + 255) / 256), 256, 0, stream>>>(
        xhC, 1024, Wg, 1024, Gf, 1536, 1, 1536, 1024);
  }
  {
    long waves = 16L * 512;
    k_dot_f32<<<(int)((waves * 64 + 255) / 256), 256, 0, stream>>>(
        CupA, 512, wf_w + 512, 1024, Fc, 512, 16, 512, 512);
  }
  k_combine4<<<1, 256, 0, stream>>>(Fc, FxAll, wf_b, CupA, Fpart, 1);
  k_final4<<<1, 256, 0, stream>>>(
      Gf, Fpart, wi_b, wo_b, wu_b,
      (float*)d_out, (float*)d_out + 512, CbfU2, 1);
}